// Round 1
// baseline (433.203 us; speedup 1.0000x reference)
//
#include <hip/hip_runtime.h>
#include <hip/hip_bf16.h>
#include <math.h>

#define BB 8
#define NN 2048
#define HH 128
#define BN (BB*NN)   // 16384

typedef unsigned short ushort_t;

// ---------------------------------------------------------------------------
// workspace layout (bytes)
// ---------------------------------------------------------------------------
#define WS_FLAG   0
#define WS_W1T    4096                      // 128*128*4  = 65536
#define WS_W2T    (WS_W1T + 65536)          // 128*128*4  = 65536
#define WS_WIHT   (WS_W2T + 65536)          // 128*384*4  = 196608
#define WS_WHHT   (WS_WIHT + 196608)        // 128*384*4  = 196608
#define WS_B1     (WS_WHHT + 196608)        // 512
#define WS_B2     (WS_B1 + 512)             // 512
#define WS_BIH    (WS_B2 + 512)             // 1536
#define WS_BHH    (WS_BIH + 1536)           // 1536
#define WS_M      532480                    // == WS_BHH+1536, 4096-aligned

template<bool BF16>
__device__ __forceinline__ float ldf(const void* p, size_t off) {
    if constexpr (BF16) return (float)((const __bf16*)p)[off];
    else                return ((const float*)p)[off];
}

// load 4 consecutive elements as float4 (bf16 widened via bit-shift)
template<bool BF16>
__device__ __forceinline__ float4 ld4(const void* p, size_t off) {
    if constexpr (BF16) {
        const ushort4 u = *reinterpret_cast<const ushort4*>((const ushort_t*)p + off);
        float4 r;
        r.x = __uint_as_float((unsigned)u.x << 16);
        r.y = __uint_as_float((unsigned)u.y << 16);
        r.z = __uint_as_float((unsigned)u.z << 16);
        r.w = __uint_as_float((unsigned)u.w << 16);
        return r;
    } else {
        return *reinterpret_cast<const float4*>((const float*)p + off);
    }
}

__device__ __forceinline__ float f4c(const float4 v, int i) {
    switch (i) { case 0: return v.x; case 1: return v.y; case 2: return v.z; default: return v.w; }
}

__device__ __forceinline__ ushort_t f2bf(float v) {
    __bf16 b = (__bf16)v;
    return *(ushort_t*)&b;
}

// ---------------------------------------------------------------------------
// detect input dtype from A's bit patterns.
// bf16 U(0,1): every ushort <= 0x3F80.  fp32: ~37% of all ushorts exceed.
// ---------------------------------------------------------------------------
__global__ void detect_kernel(const ushort_t* __restrict__ Au, int* __restrict__ flag)
{
    __shared__ int cnt;
    if (threadIdx.x == 0) cnt = 0;
    __syncthreads();
    int c = 0;
    for (int i = threadIdx.x; i < 4096; i += 256)
        if (Au[i] > 0x3F80u) ++c;
    atomicAdd(&cnt, c);
    __syncthreads();
    if (threadIdx.x == 0) *flag = (cnt < 100) ? 1 : 0;   // 1 = bf16 inputs
}

// ---------------------------------------------------------------------------
// prep: transpose all weights to fp32 W^T[k][c] in ws + widen biases to fp32.
// Kills the transposed-scatter pattern (lane==row, stride 512B) that thrashed
// L1 and amplified L2 traffic ~16x in the previous version.
// ---------------------------------------------------------------------------
template<bool BF16>
__global__ __launch_bounds__(256) void prep_kernel(
    const int* __restrict__ flag,
    const void* __restrict__ W1, const void* __restrict__ b1,
    const void* __restrict__ W2, const void* __restrict__ b2,
    const void* __restrict__ Wih, const void* __restrict__ Whh,
    const void* __restrict__ bih, const void* __restrict__ bhh,
    char* __restrict__ ws)
{
    if (*flag != (int)BF16) return;
    float* W1T  = (float*)(ws + WS_W1T);
    float* W2T  = (float*)(ws + WS_W2T);
    float* WihT = (float*)(ws + WS_WIHT);
    float* WhhT = (float*)(ws + WS_WHHT);
    float* b1f  = (float*)(ws + WS_B1);
    float* b2f  = (float*)(ws + WS_B2);
    float* bihf = (float*)(ws + WS_BIH);
    float* bhhf = (float*)(ws + WS_BHH);

    int t = blockIdx.x * 256 + threadIdx.x;
    int nth = gridDim.x * 256;
    for (int i = t; i < HH * HH; i += nth) {
        int k = i >> 7, c = i & 127;
        W1T[i] = ldf<BF16>(W1, (size_t)c * HH + k);
        W2T[i] = ldf<BF16>(W2, (size_t)c * HH + k);
    }
    for (int i = t; i < 3 * HH * HH; i += nth) {
        int k = i / 384, c = i - k * 384;
        WihT[i] = ldf<BF16>(Wih, (size_t)c * HH + k);
        WhhT[i] = ldf<BF16>(Whh, (size_t)c * HH + k);
    }
    if (t < HH)     { b1f[t] = ldf<BF16>(b1, t);  b2f[t] = ldf<BF16>(b2, t); }
    if (t < 3 * HH) { bihf[t] = ldf<BF16>(bih, t); bhhf[t] = ldf<BF16>(bhh, t); }
}

// ---------------------------------------------------------------------------
// MLP: m = relu(relu(h@W1^T+b1)@W2^T+b2), 32 rows/block, 4x4 register tiles.
// Thread (rg=tid>>5, cg=tid&31) owns rows rg*4..+3, cols cg*4..+3.
// W^T reads: lanes -> consecutive c -> coalesced; all waves share the same
// W addresses -> L1-resident, one 128KB pass per block.
// ---------------------------------------------------------------------------
template<bool BF16, bool MF32>
__global__ __launch_bounds__(256, 4) void mlp_kernel(
    const int* __restrict__ flag, const void* __restrict__ h,
    const char* __restrict__ ws, void* __restrict__ m_out)
{
    if (*flag != (int)BF16) return;
    __shared__ float hrs[32][HH];
    __shared__ float m1[32][HH];
    const float* W1T = (const float*)(ws + WS_W1T);
    const float* W2T = (const float*)(ws + WS_W2T);
    const float* b1f = (const float*)(ws + WS_B1);
    const float* b2f = (const float*)(ws + WS_B2);

    int tid = threadIdx.x;
    int row0 = blockIdx.x * 32;
    int rg = tid >> 5, cg = tid & 31;
    int r0 = rg * 4, c0 = cg * 4;

    // stage h rows
#pragma unroll
    for (int j = 0; j < 4; ++j) {
        int e = j * 256 + tid;            // 0..1023 float4s
        int r = e >> 5, c4 = e & 31;
        *(float4*)&hrs[r][c4 * 4] = ld4<BF16>(h, (size_t)(row0 + r) * HH + c4 * 4);
    }
    __syncthreads();

    // ---- layer 1 ----
    {
        float acc[4][4];
        float4 bv = *(const float4*)(b1f + c0);
#pragma unroll
        for (int r = 0; r < 4; ++r) {
            acc[r][0] = bv.x; acc[r][1] = bv.y; acc[r][2] = bv.z; acc[r][3] = bv.w;
        }
        for (int k = 0; k < HH; k += 4) {
            float4 av[4], wv[4];
#pragma unroll
            for (int r = 0; r < 4; ++r) av[r] = *(const float4*)&hrs[r0 + r][k];
#pragma unroll
            for (int kk = 0; kk < 4; ++kk) wv[kk] = *(const float4*)(W1T + (size_t)(k + kk) * HH + c0);
#pragma unroll
            for (int kk = 0; kk < 4; ++kk) {
                float4 w = wv[kk];
#pragma unroll
                for (int r = 0; r < 4; ++r) {
                    float a = f4c(av[r], kk);
                    acc[r][0] = fmaf(a, w.x, acc[r][0]);
                    acc[r][1] = fmaf(a, w.y, acc[r][1]);
                    acc[r][2] = fmaf(a, w.z, acc[r][2]);
                    acc[r][3] = fmaf(a, w.w, acc[r][3]);
                }
            }
        }
        __syncthreads();   // hrs no longer needed by anyone before overwrite? (kept: m1 separate)
#pragma unroll
        for (int r = 0; r < 4; ++r)
#pragma unroll
            for (int j = 0; j < 4; ++j)
                m1[r0 + r][c0 + j] = fmaxf(acc[r][j], 0.f);
    }
    __syncthreads();

    // ---- layer 2 ----
    {
        float acc[4][4];
        float4 bv = *(const float4*)(b2f + c0);
#pragma unroll
        for (int r = 0; r < 4; ++r) {
            acc[r][0] = bv.x; acc[r][1] = bv.y; acc[r][2] = bv.z; acc[r][3] = bv.w;
        }
        for (int k = 0; k < HH; k += 4) {
            float4 av[4], wv[4];
#pragma unroll
            for (int r = 0; r < 4; ++r) av[r] = *(const float4*)&m1[r0 + r][k];
#pragma unroll
            for (int kk = 0; kk < 4; ++kk) wv[kk] = *(const float4*)(W2T + (size_t)(k + kk) * HH + c0);
#pragma unroll
            for (int kk = 0; kk < 4; ++kk) {
                float4 w = wv[kk];
#pragma unroll
                for (int r = 0; r < 4; ++r) {
                    float a = f4c(av[r], kk);
                    acc[r][0] = fmaf(a, w.x, acc[r][0]);
                    acc[r][1] = fmaf(a, w.y, acc[r][1]);
                    acc[r][2] = fmaf(a, w.z, acc[r][2]);
                    acc[r][3] = fmaf(a, w.w, acc[r][3]);
                }
            }
        }
#pragma unroll
        for (int r = 0; r < 4; ++r) {
            float t0 = fmaxf(acc[r][0], 0.f), t1 = fmaxf(acc[r][1], 0.f);
            float t2 = fmaxf(acc[r][2], 0.f), t3 = fmaxf(acc[r][3], 0.f);
            size_t o = (size_t)(row0 + r0 + r) * HH + c0;
            if constexpr (MF32) {
                *(float4*)((float*)m_out + o) = make_float4(t0, t1, t2, t3);
            } else {
                ushort4 u; u.x = f2bf(t0); u.y = f2bf(t1); u.z = f2bf(t2); u.w = f2bf(t3);
                *(ushort4*)((ushort_t*)m_out + o) = u;
            }
        }
    }
}

// ---------------------------------------------------------------------------
// fused: msg = relu(A@m) (K=2048, LDS-tiled) then GRU gates in registers.
// 32 rows/block, 512 blocks (b = blockIdx&7 for XCD-local A/m/W L2 reuse).
// LDS 56KB static -> 2 blocks/CU. msgs overlays the dead m-tile after phase 1.
// ---------------------------------------------------------------------------
template<bool BF16, bool MF32>
__global__ __launch_bounds__(256, 2) void fused_kernel(
    const int* __restrict__ flag, const void* __restrict__ A,
    const void* __restrict__ h, const char* __restrict__ ws,
    const void* __restrict__ m_in, void* __restrict__ out)
{
    if (*flag != (int)BF16) return;
    __shared__ float As[32][64];       // A tile: 32 rows x 64 k  (8 KB)
    __shared__ float ms[64][HH];       // m tile: 64 k x 128 cols (32 KB)
    __shared__ float hrs[32][HH];      // h rows (16 KB)
    float (*msgs)[HH] = (float(*)[HH])ms;   // overlay: valid after phase 1

    const float* WihT = (const float*)(ws + WS_WIHT);
    const float* WhhT = (const float*)(ws + WS_WHHT);
    const float* bihf = (const float*)(ws + WS_BIH);
    const float* bhhf = (const float*)(ws + WS_BHH);

    int tid = threadIdx.x;
    int b = blockIdx.x & 7, rt = blockIdx.x >> 3;
    int n0 = rt * 32;
    int rg = tid >> 5, cg = tid & 31;
    int r0 = rg * 4, c0 = cg * 4;

    // stage h rows (used in gate phase + final combine)
#pragma unroll
    for (int j = 0; j < 4; ++j) {
        int e = j * 256 + tid;
        int r = e >> 5, c4 = e & 31;
        *(float4*)&hrs[r][c4 * 4] = ld4<BF16>(h, ((size_t)(b * NN + n0 + r)) * HH + c4 * 4);
    }

    // ---- phase 1: msg = relu(A[rows] @ m), K tiled by 64 ----
    float acc[4][4];
#pragma unroll
    for (int r = 0; r < 4; ++r)
#pragma unroll
        for (int j = 0; j < 4; ++j) acc[r][j] = 0.f;

    const size_t arow = (size_t)b * NN + n0;       // A row base
    const size_t mbase = (size_t)b * NN * HH;      // m batch base

    for (int kt = 0; kt < NN / 64; ++kt) {
        // stage A tile: 512 float4s, 2/thread; lane-contiguous within rows
#pragma unroll
        for (int j = 0; j < 2; ++j) {
            int e = j * 256 + tid;
            int r = e >> 4, k4 = e & 15;
            *(float4*)&As[r][k4 * 4] = ld4<BF16>(A, (arow + r) * NN + kt * 64 + k4 * 4);
        }
        // stage m tile: 2048 float4s, 8/thread; coalesced
#pragma unroll
        for (int j = 0; j < 8; ++j) {
            int e = j * 256 + tid;
            int r = e >> 5, c4 = e & 31;
            *(float4*)&ms[r][c4 * 4] = ld4<!MF32>(m_in, mbase + (size_t)(kt * 64 + r) * HH + c4 * 4);
        }
        __syncthreads();

        for (int k = 0; k < 64; k += 4) {
            float4 av[4], mv[4];
#pragma unroll
            for (int r = 0; r < 4; ++r) av[r] = *(const float4*)&As[r0 + r][k];   // wave-broadcast
#pragma unroll
            for (int kk = 0; kk < 4; ++kk) mv[kk] = *(const float4*)&ms[k + kk][c0];
#pragma unroll
            for (int kk = 0; kk < 4; ++kk) {
                float4 m4 = mv[kk];
#pragma unroll
                for (int r = 0; r < 4; ++r) {
                    float a = f4c(av[r], kk);
                    acc[r][0] = fmaf(a, m4.x, acc[r][0]);
                    acc[r][1] = fmaf(a, m4.y, acc[r][1]);
                    acc[r][2] = fmaf(a, m4.z, acc[r][2]);
                    acc[r][3] = fmaf(a, m4.w, acc[r][3]);
                }
            }
        }
        __syncthreads();
    }

    // write msg (relu) into the overlay; ms is dead now
#pragma unroll
    for (int r = 0; r < 4; ++r)
#pragma unroll
        for (int j = 0; j < 4; ++j)
            msgs[r0 + r][c0 + j] = fmaxf(acc[r][j], 0.f);
    __syncthreads();

    // ---- phase 2: GRU gates, all in registers ----
    // pr/pz: fused gx+gh pre-activations; xn/hn kept separate (n-gate needs r*gh_n)
    float pr[4][4], pz[4][4], xn[4][4], hn[4][4];
    {
        float4 bxr = *(const float4*)(bihf + c0);
        float4 bhr = *(const float4*)(bhhf + c0);
        float4 bxz = *(const float4*)(bihf + 128 + c0);
        float4 bhz = *(const float4*)(bhhf + 128 + c0);
        float4 bxn = *(const float4*)(bihf + 256 + c0);
        float4 bhn = *(const float4*)(bhhf + 256 + c0);
#pragma unroll
        for (int r = 0; r < 4; ++r)
#pragma unroll
            for (int j = 0; j < 4; ++j) {
                pr[r][j] = f4c(bxr, j) + f4c(bhr, j);
                pz[r][j] = f4c(bxz, j) + f4c(bhz, j);
                xn[r][j] = f4c(bxn, j);
                hn[r][j] = f4c(bhn, j);
            }
    }

    for (int k = 0; k < HH; k += 4) {
        float4 mg[4], hg[4];
#pragma unroll
        for (int r = 0; r < 4; ++r) {
            mg[r] = *(const float4*)&msgs[r0 + r][k];
            hg[r] = *(const float4*)&hrs[r0 + r][k];
        }
#pragma unroll
        for (int kk = 0; kk < 4; ++kk) {
            const float* wb = WihT + (size_t)(k + kk) * 384 + c0;
            const float* hb = WhhT + (size_t)(k + kk) * 384 + c0;
            float4 wxr = *(const float4*)(wb);
            float4 wxz = *(const float4*)(wb + 128);
            float4 wxn = *(const float4*)(wb + 256);
            float4 whr = *(const float4*)(hb);
            float4 whz = *(const float4*)(hb + 128);
            float4 whn = *(const float4*)(hb + 256);
#pragma unroll
            for (int r = 0; r < 4; ++r) {
                float mv = f4c(mg[r], kk);
                float hv = f4c(hg[r], kk);
                pr[r][0] = fmaf(mv, wxr.x, fmaf(hv, whr.x, pr[r][0]));
                pr[r][1] = fmaf(mv, wxr.y, fmaf(hv, whr.y, pr[r][1]));
                pr[r][2] = fmaf(mv, wxr.z, fmaf(hv, whr.z, pr[r][2]));
                pr[r][3] = fmaf(mv, wxr.w, fmaf(hv, whr.w, pr[r][3]));
                pz[r][0] = fmaf(mv, wxz.x, fmaf(hv, whz.x, pz[r][0]));
                pz[r][1] = fmaf(mv, wxz.y, fmaf(hv, whz.y, pz[r][1]));
                pz[r][2] = fmaf(mv, wxz.z, fmaf(hv, whz.z, pz[r][2]));
                pz[r][3] = fmaf(mv, wxz.w, fmaf(hv, whz.w, pz[r][3]));
                xn[r][0] = fmaf(mv, wxn.x, xn[r][0]);
                xn[r][1] = fmaf(mv, wxn.y, xn[r][1]);
                xn[r][2] = fmaf(mv, wxn.z, xn[r][2]);
                xn[r][3] = fmaf(mv, wxn.w, xn[r][3]);
                hn[r][0] = fmaf(hv, whn.x, hn[r][0]);
                hn[r][1] = fmaf(hv, whn.y, hn[r][1]);
                hn[r][2] = fmaf(hv, whn.z, hn[r][2]);
                hn[r][3] = fmaf(hv, whn.w, hn[r][3]);
            }
        }
    }

    // ---- GRU combine + store ----
#pragma unroll
    for (int r = 0; r < 4; ++r) {
        float res[4];
#pragma unroll
        for (int j = 0; j < 4; ++j) {
            float rr = 1.f / (1.f + expf(-pr[r][j]));
            float zz = 1.f / (1.f + expf(-pz[r][j]));
            float nv = tanhf(xn[r][j] + rr * hn[r][j]);
            res[j] = (1.f - zz) * nv + zz * hrs[r0 + r][c0 + j];
        }
        size_t o = ((size_t)(b * NN + n0 + r0 + r)) * HH + c0;
        if constexpr (BF16) {
            ushort4 u; u.x = f2bf(res[0]); u.y = f2bf(res[1]); u.z = f2bf(res[2]); u.w = f2bf(res[3]);
            *(ushort4*)((ushort_t*)out + o) = u;
        } else {
            *(float4*)((float*)out + o) = make_float4(res[0], res[1], res[2], res[3]);
        }
    }
}

// ---------------------------------------------------------------------------
// diagnostic fill
// ---------------------------------------------------------------------------
__global__ void diag_kernel(float* __restrict__ out, float val, int nfill)
{
    int i = blockIdx.x * 256 + threadIdx.x;
    if (i < nfill) out[i] = val;
}

// ---------------------------------------------------------------------------
extern "C" void kernel_launch(void* const* d_in, const int* in_sizes, int n_in,
                              void* d_out, int out_size, void* d_ws, size_t ws_size,
                              hipStream_t stream)
{
    const int expected[10] = {BN * HH, BB * NN * NN, HH * HH, HH, HH * HH, HH,
                              3 * HH * HH, 3 * HH * HH, 3 * HH, 3 * HH};
    int bad = -1;
    if (n_in < 10) bad = 50;
    else {
        for (int i = 0; i < 10; ++i)
            if (in_sizes[i] != expected[i]) { bad = i; break; }
    }
    if (bad < 0 && out_size != BN * HH) bad = 60;
    if (bad >= 0) {
        float val = 10000.0f + 1000.0f * (float)bad;
        int nfill = out_size / 2;
        diag_kernel<<<(nfill + 255) / 256, 256, 0, stream>>>((float*)d_out, val, nfill);
        return;
    }

    const void* h   = d_in[0];
    const void* A   = d_in[1];
    const void* W1  = d_in[2];
    const void* b1  = d_in[3];
    const void* W2  = d_in[4];
    const void* b2  = d_in[5];
    const void* Wih = d_in[6];
    const void* Whh = d_in[7];
    const void* bih = d_in[8];
    const void* bhh = d_in[9];

    const size_t need_bf  = WS_M + (size_t)BN * HH * 2;   // bf16 m intermediate
    const size_t need_f32 = WS_M + (size_t)BN * HH * 4;   // fp32 m intermediate
    if (ws_size < need_bf) {
        float val = 2000.0f + (float)(ws_size >> 10);
        int nfill = out_size / 2;
        diag_kernel<<<(nfill + 255) / 256, 256, 0, stream>>>((float*)d_out, val, nfill);
        return;
    }
    const bool mf32 = (ws_size >= need_f32);
    int*  flag = (int*)d_ws;
    char* ws   = (char*)d_ws;
    void* m    = (void*)(ws + WS_M);

    detect_kernel<<<1, 256, 0, stream>>>((const ushort_t*)A, flag);

    prep_kernel<true ><<<64, 256, 0, stream>>>(flag, W1, b1, W2, b2, Wih, Whh, bih, bhh, ws);
    prep_kernel<false><<<64, 256, 0, stream>>>(flag, W1, b1, W2, b2, Wih, Whh, bih, bhh, ws);

    if (mf32) {
        mlp_kernel<true,  true ><<<BN / 32, 256, 0, stream>>>(flag, h, ws, m);
        mlp_kernel<false, true ><<<BN / 32, 256, 0, stream>>>(flag, h, ws, m);
        fused_kernel<true,  true ><<<BB * (NN / 32), 256, 0, stream>>>(flag, A, h, ws, m, d_out);
        fused_kernel<false, true ><<<BB * (NN / 32), 256, 0, stream>>>(flag, A, h, ws, m, d_out);
    } else {
        mlp_kernel<true,  false><<<BN / 32, 256, 0, stream>>>(flag, h, ws, m);
        mlp_kernel<false, false><<<BN / 32, 256, 0, stream>>>(flag, h, ws, m);
        fused_kernel<true,  false><<<BB * (NN / 32), 256, 0, stream>>>(flag, A, h, ws, m, d_out);
        fused_kernel<false, false><<<BB * (NN / 32), 256, 0, stream>>>(flag, A, h, ws, m, d_out);
    }
}